// Round 7
// baseline (1282.748 us; speedup 1.0000x reference)
//
#include <hip/hip_runtime.h>
#include <math.h>

typedef unsigned short u16;
typedef __attribute__((ext_vector_type(8))) short bfrag;     // 8 bf16 = 4 VGPRs
typedef __attribute__((ext_vector_type(4))) float f32x4;     // MFMA acc
typedef __attribute__((ext_vector_type(4))) unsigned short us4;

#define B_SZ 32
#define L_SZ 3136
#define C_SZ 256
#define NHEADS 8
#define HID_SZ 1024
#define NW 49
#define NWIN 64
#define SHIFT 24
#define M_SZ (B_SZ * L_SZ)          // 100352
#define SCALEF 0.17677669529663687f // (256/8)^-0.5

__device__ __forceinline__ float bf2f(u16 u) {
  union { unsigned int i; float f; } v; v.i = ((unsigned)u) << 16; return v.f;
}
__device__ __forceinline__ u16 f2bf(float f) {
  union { unsigned int i; float f; } v; v.f = f;
  return (u16)((v.i + 0x7fffu + ((v.i >> 16) & 1u)) >> 16);
}
// async global->LDS, 16B per lane; LDS dest = wave-uniform base + lane*16
__device__ __forceinline__ void gload_lds16(const u16* g, u16* l) {
  __builtin_amdgcn_global_load_lds(
      (const __attribute__((address_space(1))) unsigned int*)g,
      (__attribute__((address_space(3))) unsigned int*)l, 16, 0, 0);
}

// ---------------- weight transpose: (K,N) f32 -> (N,K) bf16 row-major --------
__global__ void transpose_kernel(const float* __restrict__ in, u16* __restrict__ out,
                                 int K, int N) {
  const int idx = blockIdx.x * 256 + threadIdx.x;
  if (idx >= K * N) return;
  const int n = idx / K;
  const int k = idx - n * K;
  out[idx] = f2bf(in[(size_t)k * N + n]);
}

// ---------------- relative-position bias gather: (64,8,49,49) f32 ------------
__global__ void bias_kernel(const float* __restrict__ tab, const int* __restrict__ rel,
                            float* __restrict__ bm) {
  const int idx = blockIdx.x * 256 + threadIdx.x;
  const int tot = NWIN * NHEADS * NW * NW;
  if (idx >= tot) return;
  const int w = idx / (NHEADS * NW * NW);
  const int r = idx - w * (NHEADS * NW * NW);
  const int h = r / (NW * NW);
  const int ij = r - h * (NW * NW);
  bm[idx] = tab[(size_t)rel[w * NW * NW + ij] * NHEADS + h];
}

// ---------------- LayerNorm1 (f32 in) + +SHIFT roll; 4 rows/wave for ILP -----
__global__ __launch_bounds__(256) void ln1_kernel(
    const float* __restrict__ x, const float* __restrict__ w,
    const float* __restrict__ b, u16* __restrict__ out) {
  const int wv = threadIdx.x >> 6;
  const int lane = threadIdx.x & 63;
  const int row0 = blockIdx.x * 16 + wv * 4;
  float4 u[4];
#pragma unroll
  for (int r = 0; r < 4; ++r)
    u[r] = *((const float4*)x + (size_t)(row0 + r) * 64 + lane);
  float s[4], sq[4];
#pragma unroll
  for (int r = 0; r < 4; ++r) {
    s[r]  = u[r].x + u[r].y + u[r].z + u[r].w;
    sq[r] = u[r].x * u[r].x + u[r].y * u[r].y + u[r].z * u[r].z + u[r].w * u[r].w;
  }
#pragma unroll
  for (int d = 1; d < 64; d <<= 1)
#pragma unroll
    for (int r = 0; r < 4; ++r) {
      s[r] += __shfl_xor(s[r], d); sq[r] += __shfl_xor(sq[r], d);
    }
  float wv4[4], bv4[4];
#pragma unroll
  for (int j = 0; j < 4; ++j) { wv4[j] = w[lane * 4 + j]; bv4[j] = b[lane * 4 + j]; }
#pragma unroll
  for (int r = 0; r < 4; ++r) {
    const int row = row0 + r;
    const float mu = s[r] * (1.0f / C_SZ);
    const float rs = rsqrtf(sq[r] * (1.0f / C_SZ) - mu * mu + 1e-5f);
    const int bb = row / L_SZ;
    int l2 = row - bb * L_SZ + SHIFT;
    if (l2 >= L_SZ) l2 -= L_SZ;
    const float vv[4] = {u[r].x, u[r].y, u[r].z, u[r].w};
    us4 ov;
#pragma unroll
    for (int j = 0; j < 4; ++j) ov[j] = f2bf((vv[j] - mu) * rs * wv4[j] + bv4[j]);
    *(us4*)(out + ((size_t)bb * L_SZ + l2) * C_SZ + lane * 4) = ov;
  }
}

// ---------------- tiled MFMA GEMM: C = A(MxK) * Bt(NxK)^T + bias -------------
// Staging: global_load_lds 16B/lane, LDS linear, XOR-swizzle folded into the
// per-lane GLOBAL source address (inverse-swz source + swz read).
// MODE 0 (qkv): cols<512 -> QK buf (stride 512); cols>=512 -> V^T scatter
//   vt[((widx*8+h)*32+d)*64 + kk],  widx=row/49, kk=row%49, pad kk 49..63 unused
// MODE 1 (proj): un-roll + f32 x residual -> bf16 out
#define BM 128
#define BN 128
#define BKT 64

template <int MODE>
__global__ __launch_bounds__(256, 2) void gemm_kernel(
    const u16* __restrict__ A, const u16* __restrict__ Bt,
    const float* __restrict__ bias, int N, int K, void* __restrict__ Cout,
    const float* __restrict__ resx, u16* __restrict__ vt) {
  __shared__ u16 Als[BM * BKT];
  __shared__ u16 Bls[BN * BKT];
  const int tid = threadIdx.x;
  const int lane = tid & 63;
  const int lr = lane & 15;
  const int lg = lane >> 4;
  const int m0 = blockIdx.y * BM;
  const int n0 = blockIdx.x * BN;
  const int wid = tid >> 6;
  const int wm = (wid >> 1) * 64;
  const int wn = (wid & 1) * 64;

  const int grow = lane >> 3;              // row within 8-row group
  const int gch = (lane & 7) ^ grow;       // pre-swizzled source k-chunk

  const f32x4 fzero = {0.f, 0.f, 0.f, 0.f};
  f32x4 acc[4][4];
#pragma unroll
  for (int i = 0; i < 4; ++i)
#pragma unroll
    for (int j = 0; j < 4; ++j) acc[i][j] = fzero;

  const u16* Agl = A + (size_t)m0 * K + gch * 8;
  const u16* Bgl = Bt + (size_t)n0 * K + gch * 8;

  for (int k0 = 0; k0 < K; k0 += BKT) {
#pragma unroll
    for (int g = 0; g < 4; ++g) {
      const int rbase = wid * 32 + g * 8;
      gload_lds16(Agl + (size_t)(rbase + grow) * K + k0, Als + rbase * 64);
      gload_lds16(Bgl + (size_t)(rbase + grow) * K + k0, Bls + rbase * 64);
    }
    __syncthreads();
#pragma unroll
    for (int s = 0; s < 2; ++s) {
      const int kg = s * 4 + lg;
      bfrag af[4], bfv[4];
#pragma unroll
      for (int m = 0; m < 4; ++m) {
        const int r = wm + m * 16 + lr;
        af[m] = *(const bfrag*)(Als + r * 64 + ((kg ^ (r & 7)) * 8));
      }
#pragma unroll
      for (int n = 0; n < 4; ++n) {
        const int r = wn + n * 16 + lr;
        bfv[n] = *(const bfrag*)(Bls + r * 64 + ((kg ^ (r & 7)) * 8));
      }
#pragma unroll
      for (int m = 0; m < 4; ++m)
#pragma unroll
        for (int n = 0; n < 4; ++n)
          acc[m][n] = __builtin_amdgcn_mfma_f32_16x16x32_bf16(af[m], bfv[n],
                                                              acc[m][n], 0, 0, 0);
    }
    __syncthreads();
  }

  float bv4[4];
#pragma unroll
  for (int n = 0; n < 4; ++n) bv4[n] = bias[n0 + wn + n * 16 + lr];

#pragma unroll
  for (int m = 0; m < 4; ++m) {
#pragma unroll
    for (int i = 0; i < 4; ++i) {
      const int row = m0 + wm + m * 16 + lg * 4 + i;
      if (MODE == 1) {
        const int bb = row / L_SZ;
        int l2 = row - bb * L_SZ - SHIFT;
        if (l2 < 0) l2 += L_SZ;
        const size_t orow = (size_t)bb * L_SZ + l2;
#pragma unroll
        for (int n = 0; n < 4; ++n) {
          const int col = n0 + wn + n * 16 + lr;
          ((u16*)Cout)[orow * N + col] =
              f2bf(resx[orow * N + col] + acc[m][n][i] + bv4[n]);
        }
      } else {  // MODE 0
        if (n0 + wn < 512) {
#pragma unroll
          for (int n = 0; n < 4; ++n) {
            const int col = n0 + wn + n * 16 + lr;
            ((u16*)Cout)[(size_t)row * 512 + col] = f2bf(acc[m][n][i] + bv4[n]);
          }
        } else {
          const unsigned widx = (unsigned)row / 49u;
          const int kk = row - (int)widx * 49;
#pragma unroll
          for (int n = 0; n < 4; ++n) {
            const int col = n0 + wn + n * 16 + lr - 512;
            const int hh = col >> 5;
            const int d = col & 31;
            vt[(((size_t)widx * NHEADS + hh) * 32 + d) * 64 + kk] =
                f2bf(acc[m][n][i] + bv4[n]);
          }
        }
      }
    }
  }
}

// ---------------- windowed attention: 1 block / window, wave = 2 heads -------
// Q,K from qk buf (stride 512); V fragments direct from vt (V^T layout).
__global__ __launch_bounds__(256) void attn_kernel(const u16* __restrict__ qk,
                                                   const u16* __restrict__ vt,
                                                   const float* __restrict__ bm,
                                                   u16* __restrict__ out) {
  __shared__ u16 Pls[4][64 * 72];  // per-wave P tile, stride 72 (144B = 9x16B)
  const int widx = blockIdx.x;
  const int w = widx & (NWIN - 1);
  const int wv = threadIdx.x >> 6;
  const int lane = threadIdx.x & 63;
  const int lr = lane & 15;
  const int lg = lane >> 4;
  const size_t base = (size_t)widx * NW;
  u16* P = Pls[wv];
  const f32x4 fzero = {0.f, 0.f, 0.f, 0.f};

  for (int rep = 0; rep < 2; ++rep) {
    const int h = wv * 2 + rep;
    bfrag qf[4], kf[4];
#pragma unroll
    for (int m = 0; m < 4; ++m) {
      int r = m * 16 + lr; if (r > NW - 1) r = NW - 1;  // clamp pad rows
      qf[m] = *(const bfrag*)(qk + (base + r) * 512 + h * 32 + lg * 8);
      kf[m] = *(const bfrag*)(qk + (base + r) * 512 + 256 + h * 32 + lg * 8);
    }
    f32x4 s[4][4];
#pragma unroll
    for (int m = 0; m < 4; ++m)
#pragma unroll
      for (int n = 0; n < 4; ++n)
        s[m][n] = __builtin_amdgcn_mfma_f32_16x16x32_bf16(qf[m], kf[n], fzero, 0, 0, 0);

    const float* bh = bm + (size_t)(w * NHEADS + h) * (NW * NW);
#pragma unroll
    for (int m = 0; m < 4; ++m) {
#pragma unroll
      for (int i = 0; i < 4; ++i) {
        const int row = m * 16 + lg * 4 + i;
        const int brow = row > NW - 1 ? NW - 1 : row;
        float vals[4];
#pragma unroll
        for (int n = 0; n < 4; ++n) {
          const int c = n * 16 + lr;
          vals[n] = (c < NW) ? (s[m][n][i] * SCALEF + bh[brow * NW + c]) : -1e30f;
        }
        float mx = fmaxf(fmaxf(vals[0], vals[1]), fmaxf(vals[2], vals[3]));
#pragma unroll
        for (int d = 1; d < 16; d <<= 1) mx = fmaxf(mx, __shfl_xor(mx, d));
        float sum = 0.f;
#pragma unroll
        for (int n = 0; n < 4; ++n) { vals[n] = __expf(vals[n] - mx); sum += vals[n]; }
#pragma unroll
        for (int d = 1; d < 16; d <<= 1) sum += __shfl_xor(sum, d);
        const float inv = 1.0f / sum;
#pragma unroll
        for (int n = 0; n < 4; ++n)
          P[row * 72 + n * 16 + lr] = f2bf(vals[n] * inv);
      }
    }
    // PV: B-frags direct 16B loads from V^T (pad kk>=49 hits finite stale data,
    // multiplied by P==0)
    const u16* vth = vt + ((size_t)widx * NHEADS + h) * 32 * 64;
    f32x4 o[4][2];
#pragma unroll
    for (int m = 0; m < 4; ++m) { o[m][0] = fzero; o[m][1] = fzero; }
#pragma unroll
    for (int s2 = 0; s2 < 2; ++s2) {
      bfrag pf[4], vf[2];
#pragma unroll
      for (int m = 0; m < 4; ++m)
        pf[m] = *(const bfrag*)(P + (m * 16 + lr) * 72 + s2 * 32 + lg * 8);
#pragma unroll
      for (int n = 0; n < 2; ++n)
        vf[n] = *(const bfrag*)(vth + (size_t)(n * 16 + lr) * 64 + s2 * 32 + lg * 8);
#pragma unroll
      for (int m = 0; m < 4; ++m)
#pragma unroll
        for (int n = 0; n < 2; ++n)
          o[m][n] = __builtin_amdgcn_mfma_f32_16x16x32_bf16(pf[m], vf[n],
                                                            o[m][n], 0, 0, 0);
    }
#pragma unroll
    for (int m = 0; m < 4; ++m)
#pragma unroll
      for (int i = 0; i < 4; ++i) {
        const int row = m * 16 + lg * 4 + i;
        if (row < NW) {
#pragma unroll
          for (int n = 0; n < 2; ++n)
            out[(base + row) * C_SZ + h * 32 + n * 16 + lr] = f2bf(o[m][n][i]);
        }
      }
  }
}

// ============ FUSED: LN2 + fc1 + GELU + fc2 + residual -> f32 d_out ==========
// BM=64 rows/block, 4 waves, wave-private 16 rows. A staged via global_load_lds
// (16B-chunk XOR(r&7) swizzle, pre-swizzled source), LN'd in-LDS, then 16
// hidden-chunks of 64: fc1 (W1 B-frags from L2) -> GELU -> 2KB wave-private
// LDS transpose -> fc2 accumulate (64 VGPR). No barriers (no cross-wave deps).
__global__ __launch_bounds__(256) void mlp_kernel(
    const u16* __restrict__ x2b, const float* __restrict__ n2w,
    const float* __restrict__ n2b, const u16* __restrict__ w1t,
    const float* __restrict__ b1, const u16* __restrict__ w2t,
    const float* __restrict__ b2, float* __restrict__ outp) {
  __shared__ u16 As[64 * 256];
  __shared__ u16 Hs[4][16 * 64];
  const int wid = threadIdx.x >> 6;
  const int lane = threadIdx.x & 63;
  const int lr = lane & 15;
  const int lg = lane >> 4;
  const int m0 = blockIdx.x * 64;
  const f32x4 fzero = {0.f, 0.f, 0.f, 0.f};

  // ---- stage wave's 16 rows of x2b (pre-swizzled source chunks) ----
#pragma unroll
  for (int g = 0; g < 8; ++g) {
    const int rl = wid * 16 + g * 2 + (lane >> 5);     // local row
    const int sc = (lane & 31) ^ (rl & 7);             // source 16B chunk
    gload_lds16(x2b + (size_t)(m0 + rl) * 256 + sc * 8,
                As + (wid * 16 + g * 2) * 256);
  }
  asm volatile("s_waitcnt vmcnt(0)" ::: "memory");

  // ---- LN2 in-LDS (wave-private rows) ----
  {
    float wv4[4], bv4[4];
#pragma unroll
    for (int j = 0; j < 4; ++j) { wv4[j] = n2w[lane * 4 + j]; bv4[j] = n2b[lane * 4 + j]; }
    for (int rr = 0; rr < 16; ++rr) {
      const int r = wid * 16 + rr;
      u16* ap = As + r * 256 + (((lane >> 1) ^ (r & 7)) << 3) + ((lane & 1) << 2);
      us4 u = *(const us4*)ap;
      float v[4]; float s = 0.f, sq = 0.f;
#pragma unroll
      for (int j = 0; j < 4; ++j) { v[j] = bf2f(u[j]); s += v[j]; sq += v[j] * v[j]; }
#pragma unroll
      for (int d = 1; d < 64; d <<= 1) { s += __shfl_xor(s, d); sq += __shfl_xor(sq, d); }
      const float mu = s * (1.0f / C_SZ);
      const float rs = rsqrtf(sq * (1.0f / C_SZ) - mu * mu + 1e-5f);
      us4 ov;
#pragma unroll
      for (int j = 0; j < 4; ++j) ov[j] = f2bf((v[j] - mu) * rs * wv4[j] + bv4[j]);
      *(us4*)ap = ov;
    }
  }

  // ---- fc1 -> GELU -> fc2 over 16 hidden chunks of 64 ----
  f32x4 acc2[16];
#pragma unroll
  for (int n = 0; n < 16; ++n) acc2[n] = fzero;
  u16* H = Hs[wid];
  const int arow = wid * 16 + lr;           // A-frag row (wave-private)

  for (int c = 0; c < 16; ++c) {
    f32x4 acc1[4];
#pragma unroll
    for (int n = 0; n < 4; ++n) acc1[n] = fzero;
#pragma unroll
    for (int kt = 0; kt < 8; ++kt) {
      const bfrag af = *(const bfrag*)(As + arow * 256 + (((kt * 4 + lg) ^ (arow & 7)) << 3));
#pragma unroll
      for (int nl = 0; nl < 4; ++nl) {
        const bfrag bw = *(const bfrag*)(w1t + (size_t)(c * 64 + nl * 16 + lr) * 256 +
                                         kt * 32 + lg * 8);
        acc1[nl] = __builtin_amdgcn_mfma_f32_16x16x32_bf16(af, bw, acc1[nl], 0, 0, 0);
      }
    }
    // bias + exact GELU -> wave-private LDS (swizzled)
#pragma unroll
    for (int nl = 0; nl < 4; ++nl)
#pragma unroll
      for (int i = 0; i < 4; ++i) {
        const int rl = lg * 4 + i;
        const int col = nl * 16 + lr;
        float v = acc1[nl][i] + b1[c * 64 + col];
        v = 0.5f * v * (1.0f + erff(v * 0.70710678f));
        H[rl * 64 + ((((col >> 3) ^ (rl & 7))) << 3) + (col & 7)] = f2bf(v);
      }
    // fc2 partial accumulate (same-wave LDS RAW, lgkmcnt-ordered)
#pragma unroll
    for (int kt2 = 0; kt2 < 2; ++kt2) {
      const bfrag ah = *(const bfrag*)(H + lr * 64 + (((kt2 * 4 + lg) ^ (lr & 7)) << 3));
#pragma unroll
      for (int n2 = 0; n2 < 16; ++n2) {
        const bfrag bw2 = *(const bfrag*)(w2t + (size_t)(n2 * 16 + lr) * 1024 +
                                          c * 64 + kt2 * 32 + lg * 8);
        acc2[n2] = __builtin_amdgcn_mfma_f32_16x16x32_bf16(ah, bw2, acc2[n2], 0, 0, 0);
      }
    }
  }

  // ---- epilogue: + bias + bf16 residual -> f32 out ----
#pragma unroll
  for (int n2 = 0; n2 < 16; ++n2)
#pragma unroll
    for (int i = 0; i < 4; ++i) {
      const int row = m0 + wid * 16 + lg * 4 + i;
      const int col = n2 * 16 + lr;
      outp[(size_t)row * 256 + col] =
          acc2[n2][i] + b2[col] + bf2f(x2b[(size_t)row * 256 + col]);
    }
}

// -----------------------------------------------------------------------------
extern "C" void kernel_launch(void* const* d_in, const int* in_sizes, int n_in,
                              void* d_out, int out_size, void* d_ws, size_t ws_size,
                              hipStream_t stream) {
  (void)in_sizes; (void)n_in; (void)out_size; (void)ws_size;
  const float* x     = (const float*)d_in[0];
  const float* qkvw  = (const float*)d_in[1];
  const float* qkvb  = (const float*)d_in[2];
  const float* projw = (const float*)d_in[3];
  const float* projb = (const float*)d_in[4];
  const float* btab  = (const float*)d_in[5];
  const float* n1w   = (const float*)d_in[6];
  const float* n1b   = (const float*)d_in[7];
  const float* n2w   = (const float*)d_in[8];
  const float* n2b   = (const float*)d_in[9];
  const float* fc1w  = (const float*)d_in[10];
  const float* fc1b  = (const float*)d_in[11];
  const float* fc2w  = (const float*)d_in[12];
  const float* fc2b  = (const float*)d_in[13];
  const int* rel     = (const int*)d_in[14];

  // ---- workspace: ~280 MiB (< round-5's proven ~313 MiB usage) ----
  char* ws = (char*)d_ws;
  size_t off = 0;
  auto alloc = [&](size_t bytes) -> char* {
    char* p = ws + off; off += (bytes + 255) & ~(size_t)255; return p;
  };
  u16* qkvwT   = (u16*)alloc((size_t)768 * 256 * 2);
  u16* projwT  = (u16*)alloc((size_t)256 * 256 * 2);
  u16* fc1wT   = (u16*)alloc((size_t)1024 * 256 * 2);
  u16* fc2wT   = (u16*)alloc((size_t)256 * 1024 * 2);
  float* biasm = (float*)alloc((size_t)NWIN * NHEADS * NW * NW * 4);
  u16* bufh    = (u16*)alloc((size_t)M_SZ * C_SZ * 2);              // h / attn-out
  u16* x2b     = (u16*)alloc((size_t)M_SZ * C_SZ * 2);              // bf16 residual
  u16* qkbuf   = (u16*)alloc((size_t)M_SZ * 512 * 2);               // Q,K
  u16* vtbuf   = (u16*)alloc((size_t)B_SZ * NWIN * NHEADS * 32 * 64 * 2);  // V^T

  transpose_kernel<<<(256 * 768 + 255) / 256, 256, 0, stream>>>(qkvw, qkvwT, 256, 768);
  transpose_kernel<<<(256 * 256 + 255) / 256, 256, 0, stream>>>(projw, projwT, 256, 256);
  transpose_kernel<<<(256 * 1024 + 255) / 256, 256, 0, stream>>>(fc1w, fc1wT, 256, 1024);
  transpose_kernel<<<(1024 * 256 + 255) / 256, 256, 0, stream>>>(fc2w, fc2wT, 1024, 256);
  bias_kernel<<<(NWIN * NHEADS * NW * NW + 255) / 256, 256, 0, stream>>>(btab, rel, biasm);

  // LN1 + roll -> bufh (rolled window space)
  ln1_kernel<<<M_SZ / 16, 256, 0, stream>>>(x, n1w, n1b, bufh);

  // qkv projection: Q,K -> qkbuf; V -> vtbuf transposed
  gemm_kernel<0><<<dim3(768 / BN, M_SZ / BM), 256, 0, stream>>>(
      bufh, qkvwT, qkvb, 768, 256, qkbuf, nullptr, vtbuf);

  // windowed attention -> bufh
  attn_kernel<<<B_SZ * NWIN, 256, 0, stream>>>(qkbuf, vtbuf, biasm, bufh);

  // proj + un-roll + x residual -> bf16 x2
  gemm_kernel<1><<<dim3(256 / BN, M_SZ / BM), 256, 0, stream>>>(
      bufh, projwT, projb, 256, 256, x2b, x, nullptr);

  // fused LN2 + fc1 + GELU + fc2 + residual -> f32 d_out
  mlp_kernel<<<M_SZ / 64, 256, 0, stream>>>(x2b, n2w, n2b, fc1wT, fc1b,
                                            fc2wT, fc2b, (float*)d_out);
}

// Round 8
// 677.829 us; speedup vs baseline: 1.8924x; 1.8924x over previous
//
#include <hip/hip_runtime.h>
#include <math.h>

typedef unsigned short u16;
typedef __attribute__((ext_vector_type(8))) short bfrag;     // 8 bf16 = 4 VGPRs
typedef __attribute__((ext_vector_type(4))) float f32x4;     // MFMA acc
typedef __attribute__((ext_vector_type(4))) unsigned short us4;

#define B_SZ 32
#define L_SZ 3136
#define C_SZ 256
#define NHEADS 8
#define HID_SZ 1024
#define NW 49
#define NWIN 64
#define SHIFT 24
#define M_SZ (B_SZ * L_SZ)          // 100352
#define SCALEF 0.17677669529663687f // (256/8)^-0.5

__device__ __forceinline__ float bf2f(u16 u) {
  union { unsigned int i; float f; } v; v.i = ((unsigned)u) << 16; return v.f;
}
__device__ __forceinline__ u16 f2bf(float f) {
  union { unsigned int i; float f; } v; v.f = f;
  return (u16)((v.i + 0x7fffu + ((v.i >> 16) & 1u)) >> 16);
}
// async global->LDS, 16B per lane; LDS dest = wave-uniform base + lane*16
__device__ __forceinline__ void gload_lds16(const u16* g, u16* l) {
  __builtin_amdgcn_global_load_lds(
      (const __attribute__((address_space(1))) unsigned int*)g,
      (__attribute__((address_space(3))) unsigned int*)l, 16, 0, 0);
}

// ---------------- weight transpose: (K,N) f32 -> (N,K) bf16 row-major --------
__global__ void transpose_kernel(const float* __restrict__ in, u16* __restrict__ out,
                                 int K, int N) {
  const int idx = blockIdx.x * 256 + threadIdx.x;
  if (idx >= K * N) return;
  const int n = idx / K;
  const int k = idx - n * K;
  out[idx] = f2bf(in[(size_t)k * N + n]);
}

// ---------------- relative-position bias gather: (64,8,49,49) f32 ------------
__global__ void bias_kernel(const float* __restrict__ tab, const int* __restrict__ rel,
                            float* __restrict__ bm) {
  const int idx = blockIdx.x * 256 + threadIdx.x;
  const int tot = NWIN * NHEADS * NW * NW;
  if (idx >= tot) return;
  const int w = idx / (NHEADS * NW * NW);
  const int r = idx - w * (NHEADS * NW * NW);
  const int h = r / (NW * NW);
  const int ij = r - h * (NW * NW);
  bm[idx] = tab[(size_t)rel[w * NW * NW + ij] * NHEADS + h];
}

// ---------------- LayerNorm1 (f32 in) + +SHIFT roll; 4 rows/wave for ILP -----
__global__ __launch_bounds__(256) void ln1_kernel(
    const float* __restrict__ x, const float* __restrict__ w,
    const float* __restrict__ b, u16* __restrict__ out) {
  const int wv = threadIdx.x >> 6;
  const int lane = threadIdx.x & 63;
  const int row0 = blockIdx.x * 16 + wv * 4;
  float4 u[4];
#pragma unroll
  for (int r = 0; r < 4; ++r)
    u[r] = *((const float4*)x + (size_t)(row0 + r) * 64 + lane);
  float s[4], sq[4];
#pragma unroll
  for (int r = 0; r < 4; ++r) {
    s[r]  = u[r].x + u[r].y + u[r].z + u[r].w;
    sq[r] = u[r].x * u[r].x + u[r].y * u[r].y + u[r].z * u[r].z + u[r].w * u[r].w;
  }
#pragma unroll
  for (int d = 1; d < 64; d <<= 1)
#pragma unroll
    for (int r = 0; r < 4; ++r) {
      s[r] += __shfl_xor(s[r], d); sq[r] += __shfl_xor(sq[r], d);
    }
  float wv4[4], bv4[4];
#pragma unroll
  for (int j = 0; j < 4; ++j) { wv4[j] = w[lane * 4 + j]; bv4[j] = b[lane * 4 + j]; }
#pragma unroll
  for (int r = 0; r < 4; ++r) {
    const int row = row0 + r;
    const float mu = s[r] * (1.0f / C_SZ);
    const float rs = rsqrtf(sq[r] * (1.0f / C_SZ) - mu * mu + 1e-5f);
    const int bb = row / L_SZ;
    int l2 = row - bb * L_SZ + SHIFT;
    if (l2 >= L_SZ) l2 -= L_SZ;
    const float vv[4] = {u[r].x, u[r].y, u[r].z, u[r].w};
    us4 ov;
#pragma unroll
    for (int j = 0; j < 4; ++j) ov[j] = f2bf((vv[j] - mu) * rs * wv4[j] + bv4[j]);
    *(us4*)(out + ((size_t)bb * L_SZ + l2) * C_SZ + lane * 4) = ov;
  }
}

// ---------------- tiled MFMA GEMM: C = A(MxK) * Bt(NxK)^T + bias -------------
// Staging: global_load_lds 16B/lane, LDS linear, XOR-swizzle folded into the
// per-lane GLOBAL source address (inverse-swz source + swz read).
// MODE 0 (qkv): cols<512 -> QK buf (stride 512); cols>=512 -> V^T scatter
// MODE 1 (proj): un-roll + f32 x residual -> bf16 out
// MODE 3 (fc2): + bf16 residual -> f32 d_out
#define BM 128
#define BN 128
#define BKT 64

template <int MODE>
__global__ __launch_bounds__(256, 2) void gemm_kernel(
    const u16* __restrict__ A, const u16* __restrict__ Bt,
    const float* __restrict__ bias, int N, int K, void* __restrict__ Cout,
    const float* __restrict__ resx, u16* __restrict__ vt,
    const u16* __restrict__ resb2) {
  __shared__ u16 Als[BM * BKT];
  __shared__ u16 Bls[BN * BKT];
  const int tid = threadIdx.x;
  const int lane = tid & 63;
  const int lr = lane & 15;
  const int lg = lane >> 4;
  const int m0 = blockIdx.y * BM;
  const int n0 = blockIdx.x * BN;
  const int wid = tid >> 6;
  const int wm = (wid >> 1) * 64;
  const int wn = (wid & 1) * 64;

  const int grow = lane >> 3;              // row within 8-row group
  const int gch = (lane & 7) ^ grow;       // pre-swizzled source k-chunk

  const f32x4 fzero = {0.f, 0.f, 0.f, 0.f};
  f32x4 acc[4][4];
#pragma unroll
  for (int i = 0; i < 4; ++i)
#pragma unroll
    for (int j = 0; j < 4; ++j) acc[i][j] = fzero;

  const u16* Agl = A + (size_t)m0 * K + gch * 8;
  const u16* Bgl = Bt + (size_t)n0 * K + gch * 8;

  for (int k0 = 0; k0 < K; k0 += BKT) {
#pragma unroll
    for (int g = 0; g < 4; ++g) {
      const int rbase = wid * 32 + g * 8;
      gload_lds16(Agl + (size_t)(rbase + grow) * K + k0, Als + rbase * 64);
      gload_lds16(Bgl + (size_t)(rbase + grow) * K + k0, Bls + rbase * 64);
    }
    __syncthreads();
#pragma unroll
    for (int s = 0; s < 2; ++s) {
      const int kg = s * 4 + lg;
      bfrag af[4], bfv[4];
#pragma unroll
      for (int m = 0; m < 4; ++m) {
        const int r = wm + m * 16 + lr;
        af[m] = *(const bfrag*)(Als + r * 64 + ((kg ^ (r & 7)) * 8));
      }
#pragma unroll
      for (int n = 0; n < 4; ++n) {
        const int r = wn + n * 16 + lr;
        bfv[n] = *(const bfrag*)(Bls + r * 64 + ((kg ^ (r & 7)) * 8));
      }
#pragma unroll
      for (int m = 0; m < 4; ++m)
#pragma unroll
        for (int n = 0; n < 4; ++n)
          acc[m][n] = __builtin_amdgcn_mfma_f32_16x16x32_bf16(af[m], bfv[n],
                                                              acc[m][n], 0, 0, 0);
    }
    __syncthreads();
  }

  float bv4[4];
#pragma unroll
  for (int n = 0; n < 4; ++n) bv4[n] = bias[n0 + wn + n * 16 + lr];

#pragma unroll
  for (int m = 0; m < 4; ++m) {
#pragma unroll
    for (int i = 0; i < 4; ++i) {
      const int row = m0 + wm + m * 16 + lg * 4 + i;
      if (MODE == 1) {
        const int bb = row / L_SZ;
        int l2 = row - bb * L_SZ - SHIFT;
        if (l2 < 0) l2 += L_SZ;
        const size_t orow = (size_t)bb * L_SZ + l2;
#pragma unroll
        for (int n = 0; n < 4; ++n) {
          const int col = n0 + wn + n * 16 + lr;
          ((u16*)Cout)[orow * N + col] =
              f2bf(resx[orow * N + col] + acc[m][n][i] + bv4[n]);
        }
      } else if (MODE == 3) {
#pragma unroll
        for (int n = 0; n < 4; ++n) {
          const int col = n0 + wn + n * 16 + lr;
          ((float*)Cout)[(size_t)row * N + col] =
              acc[m][n][i] + bv4[n] + bf2f(resb2[(size_t)row * N + col]);
        }
      } else {  // MODE 0
        if (n0 + wn < 512) {
#pragma unroll
          for (int n = 0; n < 4; ++n) {
            const int col = n0 + wn + n * 16 + lr;
            ((u16*)Cout)[(size_t)row * 512 + col] = f2bf(acc[m][n][i] + bv4[n]);
          }
        } else {
          const unsigned widx = (unsigned)row / 49u;
          const int kk = row - (int)widx * 49;
#pragma unroll
          for (int n = 0; n < 4; ++n) {
            const int col = n0 + wn + n * 16 + lr - 512;
            const int hh = col >> 5;
            const int d = col & 31;
            vt[(((size_t)widx * NHEADS + hh) * 32 + d) * 64 + kk] =
                f2bf(acc[m][n][i] + bv4[n]);
          }
        }
      }
    }
  }
}

// ========== FUSED fc1: LN2(in-LDS, full-K A tile) + GEMM + GELU ==============
// A staged ONCE (128x256 = whole K), slot-swizzled p = sc^(r&7); LN'd in-place;
// then 4 K-steps with single-buffer B staging. 80KB LDS -> 2 blocks/CU.
__global__ __launch_bounds__(256, 2) void fc1ln_kernel(
    const u16* __restrict__ A, const float* __restrict__ n2w,
    const float* __restrict__ n2b, const u16* __restrict__ Bt,
    const float* __restrict__ bias, u16* __restrict__ Cout) {
  __shared__ u16 Als[BM * 256];
  __shared__ u16 Bls[BN * BKT];
  const int tid = threadIdx.x;
  const int lane = tid & 63;
  const int lr = lane & 15;
  const int lg = lane >> 4;
  const int m0 = blockIdx.y * BM;
  const int n0 = blockIdx.x * BN;
  const int wid = tid >> 6;
  const int wm = (wid >> 1) * 64;
  const int wn = (wid & 1) * 64;
  const int grow = lane >> 3;
  const int gch = (lane & 7) ^ grow;
  const f32x4 fzero = {0.f, 0.f, 0.f, 0.f};

  // ---- stage full A tile (16 issues/wave; 64 slots = 2 rows per issue) ----
#pragma unroll
  for (int g = 0; g < 16; ++g) {
    const int rl = wid * 32 + g * 2 + (lane >> 5);
    const int sp = (lane & 31) ^ (rl & 7);              // pre-swizzled src slot
    gload_lds16(A + (size_t)(m0 + rl) * 256 + sp * 8, Als + (wid * 32 + g * 2) * 256);
  }
  // ---- stage B(k0=0) ----
  const u16* Bgl = Bt + (size_t)n0 * 256 + gch * 8;
#pragma unroll
  for (int g = 0; g < 4; ++g) {
    const int rbase = wid * 32 + g * 8;
    gload_lds16(Bgl + (size_t)(rbase + grow) * 256, Bls + rbase * 64);
  }
  __syncthreads();  // drains vmcnt(0)

  // ---- LN2 in-LDS: wave wid owns rows wid*32..+31 ----
  {
    float wv4[4], bv4[4];
#pragma unroll
    for (int j = 0; j < 4; ++j) { wv4[j] = n2w[lane * 4 + j]; bv4[j] = n2b[lane * 4 + j]; }
    for (int rr = 0; rr < 32; ++rr) {
      const int r = wid * 32 + rr;
      u16* ap = Als + r * 256 + (((lane >> 1) ^ (r & 7)) << 3) + ((lane & 1) << 2);
      us4 u = *(const us4*)ap;
      float v[4]; float s = 0.f, sq = 0.f;
#pragma unroll
      for (int j = 0; j < 4; ++j) { v[j] = bf2f(u[j]); s += v[j]; sq += v[j] * v[j]; }
#pragma unroll
      for (int d = 1; d < 64; d <<= 1) { s += __shfl_xor(s, d); sq += __shfl_xor(sq, d); }
      const float mu = s * (1.0f / C_SZ);
      const float rs = rsqrtf(sq * (1.0f / C_SZ) - mu * mu + 1e-5f);
      us4 ov;
#pragma unroll
      for (int j = 0; j < 4; ++j) ov[j] = f2bf((v[j] - mu) * rs * wv4[j] + bv4[j]);
      *(us4*)ap = ov;
    }
  }
  __syncthreads();

  f32x4 acc[4][4];
#pragma unroll
  for (int i = 0; i < 4; ++i)
#pragma unroll
    for (int j = 0; j < 4; ++j) acc[i][j] = fzero;

  for (int kb = 0; kb < 4; ++kb) {
#pragma unroll
    for (int s = 0; s < 2; ++s) {
      const int kg = s * 4 + lg;          // B k-group within tile
      const int gs = kb * 8 + kg;         // A global k-slot
      bfrag af[4], bfv[4];
#pragma unroll
      for (int m = 0; m < 4; ++m) {
        const int r = wm + m * 16 + lr;
        af[m] = *(const bfrag*)(Als + r * 256 + ((gs ^ (r & 7)) * 8));
      }
#pragma unroll
      for (int n = 0; n < 4; ++n) {
        const int r = wn + n * 16 + lr;
        bfv[n] = *(const bfrag*)(Bls + r * 64 + ((kg ^ (r & 7)) * 8));
      }
#pragma unroll
      for (int m = 0; m < 4; ++m)
#pragma unroll
        for (int n = 0; n < 4; ++n)
          acc[m][n] = __builtin_amdgcn_mfma_f32_16x16x32_bf16(af[m], bfv[n],
                                                              acc[m][n], 0, 0, 0);
    }
    __syncthreads();                      // all waves done reading Bls
    if (kb < 3) {
#pragma unroll
      for (int g = 0; g < 4; ++g) {
        const int rbase = wid * 32 + g * 8;
        gload_lds16(Bgl + (size_t)(rbase + grow) * 256 + (kb + 1) * BKT,
                    Bls + rbase * 64);
      }
      __syncthreads();
    }
  }

  float bv4[4];
#pragma unroll
  for (int n = 0; n < 4; ++n) bv4[n] = bias[n0 + wn + n * 16 + lr];
#pragma unroll
  for (int m = 0; m < 4; ++m)
#pragma unroll
    for (int i = 0; i < 4; ++i) {
      const int row = m0 + wm + m * 16 + lg * 4 + i;
#pragma unroll
      for (int n = 0; n < 4; ++n) {
        const int col = n0 + wn + n * 16 + lr;
        float v = acc[m][n][i] + bv4[n];
        v = 0.5f * v * (1.0f + erff(v * 0.70710678f));
        Cout[(size_t)row * HID_SZ + col] = f2bf(v);
      }
    }
}

// ---------------- windowed attention: 2 blocks / window, wave = 1 head -------
__global__ __launch_bounds__(256) void attn_kernel(const u16* __restrict__ qk,
                                                   const u16* __restrict__ vt,
                                                   const float* __restrict__ bm,
                                                   u16* __restrict__ out) {
  __shared__ u16 Pls[4][64 * 72];  // per-wave P tile, stride 72 (144B = 9x16B)
  const int widx = blockIdx.x >> 1;
  const int half = blockIdx.x & 1;
  const int w = widx & (NWIN - 1);
  const int wv = threadIdx.x >> 6;
  const int lane = threadIdx.x & 63;
  const int lr = lane & 15;
  const int lg = lane >> 4;
  const size_t base = (size_t)widx * NW;
  u16* P = Pls[wv];
  const f32x4 fzero = {0.f, 0.f, 0.f, 0.f};
  const int h = half * 4 + wv;

  bfrag qf[4], kf[4];
#pragma unroll
  for (int m = 0; m < 4; ++m) {
    int r = m * 16 + lr; if (r > NW - 1) r = NW - 1;  // clamp pad rows
    qf[m] = *(const bfrag*)(qk + (base + r) * 512 + h * 32 + lg * 8);
    kf[m] = *(const bfrag*)(qk + (base + r) * 512 + 256 + h * 32 + lg * 8);
  }
  f32x4 s[4][4];
#pragma unroll
  for (int m = 0; m < 4; ++m)
#pragma unroll
    for (int n = 0; n < 4; ++n)
      s[m][n] = __builtin_amdgcn_mfma_f32_16x16x32_bf16(qf[m], kf[n], fzero, 0, 0, 0);

  const float* bh = bm + (size_t)(w * NHEADS + h) * (NW * NW);
#pragma unroll
  for (int m = 0; m < 4; ++m) {
#pragma unroll
    for (int i = 0; i < 4; ++i) {
      const int row = m * 16 + lg * 4 + i;
      const int brow = row > NW - 1 ? NW - 1 : row;
      float vals[4];
#pragma unroll
      for (int n = 0; n < 4; ++n) {
        const int c = n * 16 + lr;
        vals[n] = (c < NW) ? (s[m][n][i] * SCALEF + bh[brow * NW + c]) : -1e30f;
      }
      float mx = fmaxf(fmaxf(vals[0], vals[1]), fmaxf(vals[2], vals[3]));
#pragma unroll
      for (int d = 1; d < 16; d <<= 1) mx = fmaxf(mx, __shfl_xor(mx, d));
      float sum = 0.f;
#pragma unroll
      for (int n = 0; n < 4; ++n) { vals[n] = __expf(vals[n] - mx); sum += vals[n]; }
#pragma unroll
      for (int d = 1; d < 16; d <<= 1) sum += __shfl_xor(sum, d);
      const float inv = 1.0f / sum;
#pragma unroll
      for (int n = 0; n < 4; ++n)
        P[row * 72 + n * 16 + lr] = f2bf(vals[n] * inv);
    }
  }
  // PV: B-frags direct 16B loads from V^T (pad kk>=49: finite stale x P==0)
  const u16* vth = vt + ((size_t)widx * NHEADS + h) * 32 * 64;
  f32x4 o[4][2];
#pragma unroll
  for (int m = 0; m < 4; ++m) { o[m][0] = fzero; o[m][1] = fzero; }
#pragma unroll
  for (int s2 = 0; s2 < 2; ++s2) {
    bfrag pf[4], vf[2];
#pragma unroll
    for (int m = 0; m < 4; ++m)
      pf[m] = *(const bfrag*)(P + (m * 16 + lr) * 72 + s2 * 32 + lg * 8);
#pragma unroll
    for (int n = 0; n < 2; ++n)
      vf[n] = *(const bfrag*)(vth + (size_t)(n * 16 + lr) * 64 + s2 * 32 + lg * 8);
#pragma unroll
    for (int m = 0; m < 4; ++m)
#pragma unroll
      for (int n = 0; n < 2; ++n)
        o[m][n] = __builtin_amdgcn_mfma_f32_16x16x32_bf16(pf[m], vf[n],
                                                          o[m][n], 0, 0, 0);
  }
#pragma unroll
  for (int m = 0; m < 4; ++m)
#pragma unroll
    for (int i = 0; i < 4; ++i) {
      const int row = m * 16 + lg * 4 + i;
      if (row < NW) {
#pragma unroll
        for (int n = 0; n < 2; ++n)
          out[(base + row) * C_SZ + h * 32 + n * 16 + lr] = f2bf(o[m][n][i]);
      }
    }
}

// -----------------------------------------------------------------------------
extern "C" void kernel_launch(void* const* d_in, const int* in_sizes, int n_in,
                              void* d_out, int out_size, void* d_ws, size_t ws_size,
                              hipStream_t stream) {
  (void)in_sizes; (void)n_in; (void)out_size;
  const float* x     = (const float*)d_in[0];
  const float* qkvw  = (const float*)d_in[1];
  const float* qkvb  = (const float*)d_in[2];
  const float* projw = (const float*)d_in[3];
  const float* projb = (const float*)d_in[4];
  const float* btab  = (const float*)d_in[5];
  const float* n1w   = (const float*)d_in[6];
  const float* n1b   = (const float*)d_in[7];
  const float* n2w   = (const float*)d_in[8];
  const float* n2b   = (const float*)d_in[9];
  const float* fc1w  = (const float*)d_in[10];
  const float* fc1b  = (const float*)d_in[11];
  const float* fc2w  = (const float*)d_in[12];
  const float* fc2b  = (const float*)d_in[13];
  const int* rel     = (const int*)d_in[14];

  // ---- workspace: head+mid ~110 MB, tail = union{attn bufs, mlp scratch} ----
  char* ws = (char*)d_ws;
  size_t off = 0;
  auto alloc = [&](size_t bytes) -> char* {
    char* p = ws + off; off += (bytes + 255) & ~(size_t)255; return p;
  };
  u16* qkvwT   = (u16*)alloc((size_t)768 * 256 * 2);
  u16* projwT  = (u16*)alloc((size_t)256 * 256 * 2);
  u16* fc1wT   = (u16*)alloc((size_t)1024 * 256 * 2);
  u16* fc2wT   = (u16*)alloc((size_t)256 * 1024 * 2);
  float* biasm = (float*)alloc((size_t)NWIN * NHEADS * NW * NW * 4);
  u16* bufh    = (u16*)alloc((size_t)M_SZ * C_SZ * 2);   // h / attn-out
  u16* x2b     = (u16*)alloc((size_t)M_SZ * C_SZ * 2);   // bf16 residual x2

  char* tail = ws + off;
  u16* qkbuf = (u16*)tail;                                    // 102.8 MB
  const size_t qk_bytes = (size_t)M_SZ * 512 * 2;
  u16* vtbuf = (u16*)(tail + qk_bytes);                       // 67.1 MB
  const size_t tail_attn = qk_bytes + (size_t)B_SZ * NWIN * NHEADS * 32 * 64 * 2;
  u16* scratch2 = (u16*)tail;                                 // overlays qk/vt
  const size_t full_scr = (size_t)M_SZ * HID_SZ * 2;          // 205.5 MB
  const size_t tail_need1 = full_scr > tail_attn ? full_scr : tail_attn;
  const int nch = (ws_size >= off + tail_need1) ? 1 : 4;      // mlp chunking
  const int mch = M_SZ / nch;

  transpose_kernel<<<(256 * 768 + 255) / 256, 256, 0, stream>>>(qkvw, qkvwT, 256, 768);
  transpose_kernel<<<(256 * 256 + 255) / 256, 256, 0, stream>>>(projw, projwT, 256, 256);
  transpose_kernel<<<(256 * 1024 + 255) / 256, 256, 0, stream>>>(fc1w, fc1wT, 256, 1024);
  transpose_kernel<<<(1024 * 256 + 255) / 256, 256, 0, stream>>>(fc2w, fc2wT, 1024, 256);
  bias_kernel<<<(NWIN * NHEADS * NW * NW + 255) / 256, 256, 0, stream>>>(btab, rel, biasm);

  // LN1 + roll -> bufh (rolled window space)
  ln1_kernel<<<M_SZ / 16, 256, 0, stream>>>(x, n1w, n1b, bufh);

  // qkv projection: Q,K -> qkbuf; V -> vtbuf transposed
  gemm_kernel<0><<<dim3(768 / BN, M_SZ / BM), 256, 0, stream>>>(
      bufh, qkvwT, qkvb, 768, 256, qkbuf, nullptr, vtbuf, nullptr);

  // windowed attention -> bufh (2 blocks per window, wave = 1 head)
  attn_kernel<<<B_SZ * NWIN * 2, 256, 0, stream>>>(qkbuf, vtbuf, biasm, bufh);

  // proj + un-roll + x residual -> bf16 x2
  gemm_kernel<1><<<dim3(256 / BN, M_SZ / BM), 256, 0, stream>>>(
      bufh, projwT, projb, 256, 256, x2b, x, nullptr, nullptr);

  // MLP per chunk: fused LN2+fc1+GELU -> scratch2; fc2 + residual -> f32 d_out
  for (int q = 0; q < nch; ++q) {
    const size_t roff = (size_t)q * mch;
    fc1ln_kernel<<<dim3(HID_SZ / BN, mch / BM), 256, 0, stream>>>(
        x2b + roff * C_SZ, n2w, n2b, fc1wT, fc1b, scratch2);
    gemm_kernel<3><<<dim3(256 / BN, mch / BM), 256, 0, stream>>>(
        scratch2, fc2wT, fc2b, 256, 1024, (float*)d_out + roff * C_SZ,
        nullptr, nullptr, x2b + roff * C_SZ);
  }
}

// Round 9
// 513.059 us; speedup vs baseline: 2.5002x; 1.3212x over previous
//
#include <hip/hip_runtime.h>
#include <math.h>

typedef unsigned short u16;
typedef __attribute__((ext_vector_type(8))) short bfrag;     // 8 bf16 = 4 VGPRs
typedef __attribute__((ext_vector_type(4))) float f32x4;     // MFMA acc
typedef __attribute__((ext_vector_type(4))) unsigned short us4;

#define B_SZ 32
#define L_SZ 3136
#define C_SZ 256
#define NHEADS 8
#define HID_SZ 1024
#define NW 49
#define NWIN 64
#define SHIFT 24
#define M_SZ (B_SZ * L_SZ)          // 100352
#define SCALEF 0.17677669529663687f // (256/8)^-0.5

__device__ __forceinline__ float bf2f(u16 u) {
  union { unsigned int i; float f; } v; v.i = ((unsigned)u) << 16; return v.f;
}
__device__ __forceinline__ u16 f2bf(float f) {
  union { unsigned int i; float f; } v; v.f = f;
  return (u16)((v.i + 0x7fffu + ((v.i >> 16) & 1u)) >> 16);
}
// async global->LDS, 16B per lane; LDS dest = wave-uniform base + lane*16
__device__ __forceinline__ void gload_lds16(const u16* g, u16* l) {
  __builtin_amdgcn_global_load_lds(
      (const __attribute__((address_space(1))) unsigned int*)g,
      (__attribute__((address_space(3))) unsigned int*)l, 16, 0, 0);
}

// ---------------- weight transpose: (K,N) f32 -> (N,K) bf16 row-major --------
__global__ void transpose_kernel(const float* __restrict__ in, u16* __restrict__ out,
                                 int K, int N) {
  const int idx = blockIdx.x * 256 + threadIdx.x;
  if (idx >= K * N) return;
  const int n = idx / K;
  const int k = idx - n * K;
  out[idx] = f2bf(in[(size_t)k * N + n]);
}

// ---------------- relative-position bias gather: (64,8,49,49) f32 ------------
__global__ void bias_kernel(const float* __restrict__ tab, const int* __restrict__ rel,
                            float* __restrict__ bm) {
  const int idx = blockIdx.x * 256 + threadIdx.x;
  const int tot = NWIN * NHEADS * NW * NW;
  if (idx >= tot) return;
  const int w = idx / (NHEADS * NW * NW);
  const int r = idx - w * (NHEADS * NW * NW);
  const int h = r / (NW * NW);
  const int ij = r - h * (NW * NW);
  bm[idx] = tab[(size_t)rel[w * NW * NW + ij] * NHEADS + h];
}

// ---------------- LayerNorm1 (f32 in) + +SHIFT roll; 4 rows/wave for ILP -----
__global__ __launch_bounds__(256) void ln1_kernel(
    const float* __restrict__ x, const float* __restrict__ w,
    const float* __restrict__ b, u16* __restrict__ out) {
  const int wv = threadIdx.x >> 6;
  const int lane = threadIdx.x & 63;
  const int row0 = blockIdx.x * 16 + wv * 4;
  float4 u[4];
#pragma unroll
  for (int r = 0; r < 4; ++r)
    u[r] = *((const float4*)x + (size_t)(row0 + r) * 64 + lane);
  float s[4], sq[4];
#pragma unroll
  for (int r = 0; r < 4; ++r) {
    s[r]  = u[r].x + u[r].y + u[r].z + u[r].w;
    sq[r] = u[r].x * u[r].x + u[r].y * u[r].y + u[r].z * u[r].z + u[r].w * u[r].w;
  }
#pragma unroll
  for (int d = 1; d < 64; d <<= 1)
#pragma unroll
    for (int r = 0; r < 4; ++r) {
      s[r] += __shfl_xor(s[r], d); sq[r] += __shfl_xor(sq[r], d);
    }
  float wv4[4], bv4[4];
#pragma unroll
  for (int j = 0; j < 4; ++j) { wv4[j] = w[lane * 4 + j]; bv4[j] = b[lane * 4 + j]; }
#pragma unroll
  for (int r = 0; r < 4; ++r) {
    const int row = row0 + r;
    const float mu = s[r] * (1.0f / C_SZ);
    const float rs = rsqrtf(sq[r] * (1.0f / C_SZ) - mu * mu + 1e-5f);
    const int bb = row / L_SZ;
    int l2 = row - bb * L_SZ + SHIFT;
    if (l2 >= L_SZ) l2 -= L_SZ;
    const float vv[4] = {u[r].x, u[r].y, u[r].z, u[r].w};
    us4 ov;
#pragma unroll
    for (int j = 0; j < 4; ++j) ov[j] = f2bf((vv[j] - mu) * rs * wv4[j] + bv4[j]);
    *(us4*)(out + ((size_t)bb * L_SZ + l2) * C_SZ + lane * 4) = ov;
  }
}

// ---------------- LayerNorm2 (bf16 in), no roll; 4 rows/wave -----------------
__global__ __launch_bounds__(256) void ln2_kernel(
    const u16* __restrict__ x, const float* __restrict__ w,
    const float* __restrict__ b, u16* __restrict__ out) {
  const int wv = threadIdx.x >> 6;
  const int lane = threadIdx.x & 63;
  const int row0 = blockIdx.x * 16 + wv * 4;
  us4 u[4];
#pragma unroll
  for (int r = 0; r < 4; ++r)
    u[r] = *(const us4*)(x + (size_t)(row0 + r) * C_SZ + lane * 4);
  float v[4][4], s[4], sq[4];
#pragma unroll
  for (int r = 0; r < 4; ++r) {
    s[r] = 0.f; sq[r] = 0.f;
#pragma unroll
    for (int j = 0; j < 4; ++j) {
      v[r][j] = bf2f(u[r][j]); s[r] += v[r][j]; sq[r] += v[r][j] * v[r][j];
    }
  }
#pragma unroll
  for (int d = 1; d < 64; d <<= 1)
#pragma unroll
    for (int r = 0; r < 4; ++r) {
      s[r] += __shfl_xor(s[r], d); sq[r] += __shfl_xor(sq[r], d);
    }
  float wv4[4], bv4[4];
#pragma unroll
  for (int j = 0; j < 4; ++j) { wv4[j] = w[lane * 4 + j]; bv4[j] = b[lane * 4 + j]; }
#pragma unroll
  for (int r = 0; r < 4; ++r) {
    const float mu = s[r] * (1.0f / C_SZ);
    const float rs = rsqrtf(sq[r] * (1.0f / C_SZ) - mu * mu + 1e-5f);
    us4 ov;
#pragma unroll
    for (int j = 0; j < 4; ++j) ov[j] = f2bf((v[r][j] - mu) * rs * wv4[j] + bv4[j]);
    *(us4*)(out + (size_t)(row0 + r) * C_SZ + lane * 4) = ov;
  }
}

// ---------------- tiled MFMA GEMM: C = A(MxK) * Bt(NxK)^T + bias -------------
// Staging: global_load_lds 16B/lane, LDS linear, XOR-swizzle folded into the
// per-lane GLOBAL source address (inverse-swz source + swz read).
// MODE 0 (qkv): cols<512 -> QK buf (stride 512); cols>=512 -> V^T scatter
// MODE 1 (proj): un-roll + f32 x residual -> bf16 out
// MODE 2 (fc1): exact GELU -> bf16
// MODE 3 (fc2): + bf16 residual -> f32 d_out
#define BM 128
#define BN 128
#define BKT 64

template <int MODE>
__global__ __launch_bounds__(256, 2) void gemm_kernel(
    const u16* __restrict__ A, const u16* __restrict__ Bt,
    const float* __restrict__ bias, int N, int K, void* __restrict__ Cout,
    const float* __restrict__ resx, u16* __restrict__ vt,
    const u16* __restrict__ resb2) {
  __shared__ u16 Als[BM * BKT];
  __shared__ u16 Bls[BN * BKT];
  const int tid = threadIdx.x;
  const int lane = tid & 63;
  const int lr = lane & 15;
  const int lg = lane >> 4;
  const int m0 = blockIdx.y * BM;
  const int n0 = blockIdx.x * BN;
  const int wid = tid >> 6;
  const int wm = (wid >> 1) * 64;
  const int wn = (wid & 1) * 64;

  const int grow = lane >> 3;              // row within 8-row group
  const int gch = (lane & 7) ^ grow;       // pre-swizzled source k-chunk

  const f32x4 fzero = {0.f, 0.f, 0.f, 0.f};
  f32x4 acc[4][4];
#pragma unroll
  for (int i = 0; i < 4; ++i)
#pragma unroll
    for (int j = 0; j < 4; ++j) acc[i][j] = fzero;

  const u16* Agl = A + (size_t)m0 * K + gch * 8;
  const u16* Bgl = Bt + (size_t)n0 * K + gch * 8;

  for (int k0 = 0; k0 < K; k0 += BKT) {
#pragma unroll
    for (int g = 0; g < 4; ++g) {
      const int rbase = wid * 32 + g * 8;
      gload_lds16(Agl + (size_t)(rbase + grow) * K + k0, Als + rbase * 64);
      gload_lds16(Bgl + (size_t)(rbase + grow) * K + k0, Bls + rbase * 64);
    }
    __syncthreads();
#pragma unroll
    for (int s = 0; s < 2; ++s) {
      const int kg = s * 4 + lg;
      bfrag af[4], bfv[4];
#pragma unroll
      for (int m = 0; m < 4; ++m) {
        const int r = wm + m * 16 + lr;
        af[m] = *(const bfrag*)(Als + r * 64 + ((kg ^ (r & 7)) * 8));
      }
#pragma unroll
      for (int n = 0; n < 4; ++n) {
        const int r = wn + n * 16 + lr;
        bfv[n] = *(const bfrag*)(Bls + r * 64 + ((kg ^ (r & 7)) * 8));
      }
#pragma unroll
      for (int m = 0; m < 4; ++m)
#pragma unroll
        for (int n = 0; n < 4; ++n)
          acc[m][n] = __builtin_amdgcn_mfma_f32_16x16x32_bf16(af[m], bfv[n],
                                                              acc[m][n], 0, 0, 0);
    }
    __syncthreads();
  }

  float bv4[4];
#pragma unroll
  for (int n = 0; n < 4; ++n) bv4[n] = bias[n0 + wn + n * 16 + lr];

#pragma unroll
  for (int m = 0; m < 4; ++m) {
#pragma unroll
    for (int i = 0; i < 4; ++i) {
      const int row = m0 + wm + m * 16 + lg * 4 + i;
      if (MODE == 1) {
        const int bb = row / L_SZ;
        int l2 = row - bb * L_SZ - SHIFT;
        if (l2 < 0) l2 += L_SZ;
        const size_t orow = (size_t)bb * L_SZ + l2;
#pragma unroll
        for (int n = 0; n < 4; ++n) {
          const int col = n0 + wn + n * 16 + lr;
          ((u16*)Cout)[orow * N + col] =
              f2bf(resx[orow * N + col] + acc[m][n][i] + bv4[n]);
        }
      } else if (MODE == 2) {
#pragma unroll
        for (int n = 0; n < 4; ++n) {
          const int col = n0 + wn + n * 16 + lr;
          float v = acc[m][n][i] + bv4[n];
          v = 0.5f * v * (1.0f + erff(v * 0.70710678f));
          ((u16*)Cout)[(size_t)row * N + col] = f2bf(v);
        }
      } else if (MODE == 3) {
#pragma unroll
        for (int n = 0; n < 4; ++n) {
          const int col = n0 + wn + n * 16 + lr;
          ((float*)Cout)[(size_t)row * N + col] =
              acc[m][n][i] + bv4[n] + bf2f(resb2[(size_t)row * N + col]);
        }
      } else {  // MODE 0
        if (n0 + wn < 512) {
#pragma unroll
          for (int n = 0; n < 4; ++n) {
            const int col = n0 + wn + n * 16 + lr;
            ((u16*)Cout)[(size_t)row * 512 + col] = f2bf(acc[m][n][i] + bv4[n]);
          }
        } else {
          const unsigned widx = (unsigned)row / 49u;
          const int kk = row - (int)widx * 49;
#pragma unroll
          for (int n = 0; n < 4; ++n) {
            const int col = n0 + wn + n * 16 + lr - 512;
            const int hh = col >> 5;
            const int d = col & 31;
            vt[(((size_t)widx * NHEADS + hh) * 32 + d) * 64 + kk] =
                f2bf(acc[m][n][i] + bv4[n]);
          }
        }
      }
    }
  }
}

// ---------------- windowed attention: 2 blocks / window, wave = 1 head -------
__global__ __launch_bounds__(256) void attn_kernel(const u16* __restrict__ qk,
                                                   const u16* __restrict__ vt,
                                                   const float* __restrict__ bm,
                                                   u16* __restrict__ out) {
  __shared__ u16 Pls[4][64 * 72];  // per-wave P tile, stride 72 (144B = 9x16B)
  const int widx = blockIdx.x >> 1;
  const int half = blockIdx.x & 1;
  const int w = widx & (NWIN - 1);
  const int wv = threadIdx.x >> 6;
  const int lane = threadIdx.x & 63;
  const int lr = lane & 15;
  const int lg = lane >> 4;
  const size_t base = (size_t)widx * NW;
  u16* P = Pls[wv];
  const f32x4 fzero = {0.f, 0.f, 0.f, 0.f};
  const int h = half * 4 + wv;

  bfrag qf[4], kf[4];
#pragma unroll
  for (int m = 0; m < 4; ++m) {
    int r = m * 16 + lr; if (r > NW - 1) r = NW - 1;  // clamp pad rows
    qf[m] = *(const bfrag*)(qk + (base + r) * 512 + h * 32 + lg * 8);
    kf[m] = *(const bfrag*)(qk + (base + r) * 512 + 256 + h * 32 + lg * 8);
  }
  f32x4 s[4][4];
#pragma unroll
  for (int m = 0; m < 4; ++m)
#pragma unroll
    for (int n = 0; n < 4; ++n)
      s[m][n] = __builtin_amdgcn_mfma_f32_16x16x32_bf16(qf[m], kf[n], fzero, 0, 0, 0);

  const float* bh = bm + (size_t)(w * NHEADS + h) * (NW * NW);
#pragma unroll
  for (int m = 0; m < 4; ++m) {
#pragma unroll
    for (int i = 0; i < 4; ++i) {
      const int row = m * 16 + lg * 4 + i;
      const int brow = row > NW - 1 ? NW - 1 : row;
      float vals[4];
#pragma unroll
      for (int n = 0; n < 4; ++n) {
        const int c = n * 16 + lr;
        vals[n] = (c < NW) ? (s[m][n][i] * SCALEF + bh[brow * NW + c]) : -1e30f;
      }
      float mx = fmaxf(fmaxf(vals[0], vals[1]), fmaxf(vals[2], vals[3]));
#pragma unroll
      for (int d = 1; d < 16; d <<= 1) mx = fmaxf(mx, __shfl_xor(mx, d));
      float sum = 0.f;
#pragma unroll
      for (int n = 0; n < 4; ++n) { vals[n] = __expf(vals[n] - mx); sum += vals[n]; }
#pragma unroll
      for (int d = 1; d < 16; d <<= 1) sum += __shfl_xor(sum, d);
      const float inv = 1.0f / sum;
#pragma unroll
      for (int n = 0; n < 4; ++n)
        P[row * 72 + n * 16 + lr] = f2bf(vals[n] * inv);
    }
  }
  // PV: B-frags direct 16B loads from V^T (pad kk>=49: finite stale x P==0)
  const u16* vth = vt + ((size_t)widx * NHEADS + h) * 32 * 64;
  f32x4 o[4][2];
#pragma unroll
  for (int m = 0; m < 4; ++m) { o[m][0] = fzero; o[m][1] = fzero; }
#pragma unroll
  for (int s2 = 0; s2 < 2; ++s2) {
    bfrag pf[4], vf[2];
#pragma unroll
    for (int m = 0; m < 4; ++m)
      pf[m] = *(const bfrag*)(P + (m * 16 + lr) * 72 + s2 * 32 + lg * 8);
#pragma unroll
    for (int n = 0; n < 2; ++n)
      vf[n] = *(const bfrag*)(vth + (size_t)(n * 16 + lr) * 64 + s2 * 32 + lg * 8);
#pragma unroll
    for (int m = 0; m < 4; ++m)
#pragma unroll
      for (int n = 0; n < 2; ++n)
        o[m][n] = __builtin_amdgcn_mfma_f32_16x16x32_bf16(pf[m], vf[n],
                                                          o[m][n], 0, 0, 0);
  }
#pragma unroll
  for (int m = 0; m < 4; ++m)
#pragma unroll
    for (int i = 0; i < 4; ++i) {
      const int row = m * 16 + lg * 4 + i;
      if (row < NW) {
#pragma unroll
        for (int n = 0; n < 2; ++n)
          out[(base + row) * C_SZ + h * 32 + n * 16 + lr] = f2bf(o[m][n][i]);
      }
    }
}

// -----------------------------------------------------------------------------
extern "C" void kernel_launch(void* const* d_in, const int* in_sizes, int n_in,
                              void* d_out, int out_size, void* d_ws, size_t ws_size,
                              hipStream_t stream) {
  (void)in_sizes; (void)n_in; (void)out_size;
  const float* x     = (const float*)d_in[0];
  const float* qkvw  = (const float*)d_in[1];
  const float* qkvb  = (const float*)d_in[2];
  const float* projw = (const float*)d_in[3];
  const float* projb = (const float*)d_in[4];
  const float* btab  = (const float*)d_in[5];
  const float* n1w   = (const float*)d_in[6];
  const float* n1b   = (const float*)d_in[7];
  const float* n2w   = (const float*)d_in[8];
  const float* n2b   = (const float*)d_in[9];
  const float* fc1w  = (const float*)d_in[10];
  const float* fc1b  = (const float*)d_in[11];
  const float* fc2w  = (const float*)d_in[12];
  const float* fc2b  = (const float*)d_in[13];
  const int* rel     = (const int*)d_in[14];

  // ---- workspace: head+mid ~110 MB, tail = union{attn bufs, mlp scratch} ----
  char* ws = (char*)d_ws;
  size_t off = 0;
  auto alloc = [&](size_t bytes) -> char* {
    char* p = ws + off; off += (bytes + 255) & ~(size_t)255; return p;
  };
  u16* qkvwT   = (u16*)alloc((size_t)768 * 256 * 2);
  u16* projwT  = (u16*)alloc((size_t)256 * 256 * 2);
  u16* fc1wT   = (u16*)alloc((size_t)1024 * 256 * 2);
  u16* fc2wT   = (u16*)alloc((size_t)256 * 1024 * 2);
  float* biasm = (float*)alloc((size_t)NWIN * NHEADS * NW * NW * 4);
  u16* bufh    = (u16*)alloc((size_t)M_SZ * C_SZ * 2);   // h / attn-out / h2
  u16* x2b     = (u16*)alloc((size_t)M_SZ * C_SZ * 2);   // bf16 residual x2

  char* tail = ws + off;
  u16* qkbuf = (u16*)tail;                                    // 102.8 MB
  const size_t qk_bytes = (size_t)M_SZ * 512 * 2;
  u16* vtbuf = (u16*)(tail + qk_bytes);                       // 67.1 MB
  const size_t tail_attn = qk_bytes + (size_t)B_SZ * NWIN * NHEADS * 32 * 64 * 2;
  u16* scratch2 = (u16*)tail;                                 // overlays qk/vt
  const size_t full_scr = (size_t)M_SZ * HID_SZ * 2;          // 205.5 MB
  const size_t tail_need1 = full_scr > tail_attn ? full_scr : tail_attn;
  const int nch = (ws_size >= off + tail_need1) ? 1 : 4;      // mlp chunking
  const int mch = M_SZ / nch;

  transpose_kernel<<<(256 * 768 + 255) / 256, 256, 0, stream>>>(qkvw, qkvwT, 256, 768);
  transpose_kernel<<<(256 * 256 + 255) / 256, 256, 0, stream>>>(projw, projwT, 256, 256);
  transpose_kernel<<<(256 * 1024 + 255) / 256, 256, 0, stream>>>(fc1w, fc1wT, 256, 1024);
  transpose_kernel<<<(1024 * 256 + 255) / 256, 256, 0, stream>>>(fc2w, fc2wT, 1024, 256);
  bias_kernel<<<(NWIN * NHEADS * NW * NW + 255) / 256, 256, 0, stream>>>(btab, rel, biasm);

  // LN1 + roll -> bufh (rolled window space)
  ln1_kernel<<<M_SZ / 16, 256, 0, stream>>>(x, n1w, n1b, bufh);

  // qkv projection: Q,K -> qkbuf; V -> vtbuf transposed
  gemm_kernel<0><<<dim3(768 / BN, M_SZ / BM), 256, 0, stream>>>(
      bufh, qkvwT, qkvb, 768, 256, qkbuf, nullptr, vtbuf, nullptr);

  // windowed attention -> bufh (2 blocks per window, wave = 1 head)
  attn_kernel<<<B_SZ * NWIN * 2, 256, 0, stream>>>(qkbuf, vtbuf, biasm, bufh);

  // proj + un-roll + x residual -> bf16 x2
  gemm_kernel<1><<<dim3(256 / BN, M_SZ / BM), 256, 0, stream>>>(
      bufh, projwT, projb, 256, 256, x2b, x, nullptr, nullptr);

  // MLP per chunk: ln2 -> bufh; fc1+GELU -> scratch2; fc2 + residual -> d_out
  for (int q = 0; q < nch; ++q) {
    const size_t roff = (size_t)q * mch;
    ln2_kernel<<<mch / 16, 256, 0, stream>>>(x2b + roff * C_SZ, n2w, n2b,
                                             bufh + roff * C_SZ);
    gemm_kernel<2><<<dim3(HID_SZ / BN, mch / BM), 256, 0, stream>>>(
        bufh + roff * C_SZ, fc1wT, fc1b, 1024, 256, scratch2, nullptr, nullptr, nullptr);
    gemm_kernel<3><<<dim3(256 / BN, mch / BM), 256, 0, stream>>>(
        scratch2, fc2wT, fc2b, 256, 1024, (float*)d_out + roff * C_SZ,
        nullptr, nullptr, x2b + roff * C_SZ);
  }
}

// Round 10
// 456.751 us; speedup vs baseline: 2.8084x; 1.1233x over previous
//
#include <hip/hip_runtime.h>
#include <math.h>

typedef unsigned short u16;
typedef __attribute__((ext_vector_type(8))) short bfrag;     // 8 bf16 = 4 VGPRs
typedef __attribute__((ext_vector_type(4))) float f32x4;     // MFMA acc
typedef __attribute__((ext_vector_type(4))) unsigned short us4;

#define B_SZ 32
#define L_SZ 3136
#define C_SZ 256
#define NHEADS 8
#define HID_SZ 1024
#define NW 49
#define NWIN 64
#define SHIFT 24
#define M_SZ (B_SZ * L_SZ)          // 100352
#define SCALEF 0.17677669529663687f // (256/8)^-0.5

__device__ __forceinline__ float bf2f(u16 u) {
  union { unsigned int i; float f; } v; v.i = ((unsigned)u) << 16; return v.f;
}
__device__ __forceinline__ u16 f2bf(float f) {
  union { unsigned int i; float f; } v; v.f = f;
  return (u16)((v.i + 0x7fffu + ((v.i >> 16) & 1u)) >> 16);
}
// async global->LDS, 16B per lane; LDS dest = wave-uniform base + lane*16
__device__ __forceinline__ void gload_lds16(const u16* g, u16* l) {
  __builtin_amdgcn_global_load_lds(
      (const __attribute__((address_space(1))) unsigned int*)g,
      (__attribute__((address_space(3))) unsigned int*)l, 16, 0, 0);
}

// ---------------- weight transpose: (K,N) f32 -> (N,K) bf16 row-major --------
__global__ void transpose_kernel(const float* __restrict__ in, u16* __restrict__ out,
                                 int K, int N) {
  const int idx = blockIdx.x * 256 + threadIdx.x;
  if (idx >= K * N) return;
  const int n = idx / K;
  const int k = idx - n * K;
  out[idx] = f2bf(in[(size_t)k * N + n]);
}

// ---------------- relative-position bias gather: (64,8,49,49) f32 ------------
__global__ void bias_kernel(const float* __restrict__ tab, const int* __restrict__ rel,
                            float* __restrict__ bm) {
  const int idx = blockIdx.x * 256 + threadIdx.x;
  const int tot = NWIN * NHEADS * NW * NW;
  if (idx >= tot) return;
  const int w = idx / (NHEADS * NW * NW);
  const int r = idx - w * (NHEADS * NW * NW);
  const int h = r / (NW * NW);
  const int ij = r - h * (NW * NW);
  bm[idx] = tab[(size_t)rel[w * NW * NW + ij] * NHEADS + h];
}

// ---------------- LayerNorm1 (f32 in) + +SHIFT roll; 4 rows/wave for ILP -----
__global__ __launch_bounds__(256) void ln1_kernel(
    const float* __restrict__ x, const float* __restrict__ w,
    const float* __restrict__ b, u16* __restrict__ out) {
  const int wv = threadIdx.x >> 6;
  const int lane = threadIdx.x & 63;
  const int row0 = blockIdx.x * 16 + wv * 4;
  float4 u[4];
#pragma unroll
  for (int r = 0; r < 4; ++r)
    u[r] = *((const float4*)x + (size_t)(row0 + r) * 64 + lane);
  float s[4], sq[4];
#pragma unroll
  for (int r = 0; r < 4; ++r) {
    s[r]  = u[r].x + u[r].y + u[r].z + u[r].w;
    sq[r] = u[r].x * u[r].x + u[r].y * u[r].y + u[r].z * u[r].z + u[r].w * u[r].w;
  }
#pragma unroll
  for (int d = 1; d < 64; d <<= 1)
#pragma unroll
    for (int r = 0; r < 4; ++r) {
      s[r] += __shfl_xor(s[r], d); sq[r] += __shfl_xor(sq[r], d);
    }
  float wv4[4], bv4[4];
#pragma unroll
  for (int j = 0; j < 4; ++j) { wv4[j] = w[lane * 4 + j]; bv4[j] = b[lane * 4 + j]; }
#pragma unroll
  for (int r = 0; r < 4; ++r) {
    const int row = row0 + r;
    const float mu = s[r] * (1.0f / C_SZ);
    const float rs = rsqrtf(sq[r] * (1.0f / C_SZ) - mu * mu + 1e-5f);
    const int bb = row / L_SZ;
    int l2 = row - bb * L_SZ + SHIFT;
    if (l2 >= L_SZ) l2 -= L_SZ;
    const float vv[4] = {u[r].x, u[r].y, u[r].z, u[r].w};
    us4 ov;
#pragma unroll
    for (int j = 0; j < 4; ++j) ov[j] = f2bf((vv[j] - mu) * rs * wv4[j] + bv4[j]);
    *(us4*)(out + ((size_t)bb * L_SZ + l2) * C_SZ + lane * 4) = ov;
  }
}

// ---------------- LayerNorm2 (bf16 in), no roll; 4 rows/wave -----------------
__global__ __launch_bounds__(256) void ln2_kernel(
    const u16* __restrict__ x, const float* __restrict__ w,
    const float* __restrict__ b, u16* __restrict__ out) {
  const int wv = threadIdx.x >> 6;
  const int lane = threadIdx.x & 63;
  const int row0 = blockIdx.x * 16 + wv * 4;
  us4 u[4];
#pragma unroll
  for (int r = 0; r < 4; ++r)
    u[r] = *(const us4*)(x + (size_t)(row0 + r) * C_SZ + lane * 4);
  float v[4][4], s[4], sq[4];
#pragma unroll
  for (int r = 0; r < 4; ++r) {
    s[r] = 0.f; sq[r] = 0.f;
#pragma unroll
    for (int j = 0; j < 4; ++j) {
      v[r][j] = bf2f(u[r][j]); s[r] += v[r][j]; sq[r] += v[r][j] * v[r][j];
    }
  }
#pragma unroll
  for (int d = 1; d < 64; d <<= 1)
#pragma unroll
    for (int r = 0; r < 4; ++r) {
      s[r] += __shfl_xor(s[r], d); sq[r] += __shfl_xor(sq[r], d);
    }
  float wv4[4], bv4[4];
#pragma unroll
  for (int j = 0; j < 4; ++j) { wv4[j] = w[lane * 4 + j]; bv4[j] = b[lane * 4 + j]; }
#pragma unroll
  for (int r = 0; r < 4; ++r) {
    const float mu = s[r] * (1.0f / C_SZ);
    const float rs = rsqrtf(sq[r] * (1.0f / C_SZ) - mu * mu + 1e-5f);
    us4 ov;
#pragma unroll
    for (int j = 0; j < 4; ++j) ov[j] = f2bf((v[r][j] - mu) * rs * wv4[j] + bv4[j]);
    *(us4*)(out + (size_t)(row0 + r) * C_SZ + lane * 4) = ov;
  }
}

// ---------------- tiled MFMA GEMM: C = A(MxK) * Bt(NxK)^T + bias -------------
// 1D grid with XCD-aware decode (bid&7 = XCD under round-robin dispatch;
// each XCD owns a contiguous M-panel range -> A-panels stay L2-resident
// across their N-blocks). REQUIRES gridDim.x % 8 == 0 (all launches comply).
// MODE 0: plain bf16 store        MODE 1 (proj): un-roll + f32 x res -> bf16
// MODE 2 (fc1): exact GELU -> bf16   MODE 3 (fc2): + bf16 res -> f32 d_out
#define BM 128
#define BN 128
#define BKT 64

template <int MODE>
__global__ __launch_bounds__(256, 2) void gemm_kernel(
    const u16* __restrict__ A, const u16* __restrict__ Bt,
    const float* __restrict__ bias, int N, int K, void* __restrict__ Cout,
    const float* __restrict__ resx, const u16* __restrict__ resb2) {
  __shared__ u16 Als[BM * BKT];
  __shared__ u16 Bls[BN * BKT];
  const int nbx = N / BN;
  const int per = gridDim.x >> 3;
  const int lin = (blockIdx.x & 7) * per + (blockIdx.x >> 3);
  const int by = lin / nbx;
  const int bx = lin - by * nbx;
  const int m0 = by * BM;
  const int n0 = bx * BN;

  const int tid = threadIdx.x;
  const int lane = tid & 63;
  const int lr = lane & 15;
  const int lg = lane >> 4;
  const int wid = tid >> 6;
  const int wm = (wid >> 1) * 64;
  const int wn = (wid & 1) * 64;

  const int grow = lane >> 3;              // row within 8-row group
  const int gch = (lane & 7) ^ grow;       // pre-swizzled source k-chunk

  const f32x4 fzero = {0.f, 0.f, 0.f, 0.f};
  f32x4 acc[4][4];
#pragma unroll
  for (int i = 0; i < 4; ++i)
#pragma unroll
    for (int j = 0; j < 4; ++j) acc[i][j] = fzero;

  const u16* Agl = A + (size_t)m0 * K + gch * 8;
  const u16* Bgl = Bt + (size_t)n0 * K + gch * 8;

  for (int k0 = 0; k0 < K; k0 += BKT) {
#pragma unroll
    for (int g = 0; g < 4; ++g) {
      const int rbase = wid * 32 + g * 8;
      gload_lds16(Agl + (size_t)(rbase + grow) * K + k0, Als + rbase * 64);
      gload_lds16(Bgl + (size_t)(rbase + grow) * K + k0, Bls + rbase * 64);
    }
    __syncthreads();
#pragma unroll
    for (int s = 0; s < 2; ++s) {
      const int kg = s * 4 + lg;
      bfrag af[4], bfv[4];
#pragma unroll
      for (int m = 0; m < 4; ++m) {
        const int r = wm + m * 16 + lr;
        af[m] = *(const bfrag*)(Als + r * 64 + ((kg ^ (r & 7)) * 8));
      }
#pragma unroll
      for (int n = 0; n < 4; ++n) {
        const int r = wn + n * 16 + lr;
        bfv[n] = *(const bfrag*)(Bls + r * 64 + ((kg ^ (r & 7)) * 8));
      }
#pragma unroll
      for (int m = 0; m < 4; ++m)
#pragma unroll
        for (int n = 0; n < 4; ++n)
          acc[m][n] = __builtin_amdgcn_mfma_f32_16x16x32_bf16(af[m], bfv[n],
                                                              acc[m][n], 0, 0, 0);
    }
    __syncthreads();
  }

  float bv4[4];
#pragma unroll
  for (int n = 0; n < 4; ++n) bv4[n] = bias[n0 + wn + n * 16 + lr];

#pragma unroll
  for (int m = 0; m < 4; ++m) {
#pragma unroll
    for (int i = 0; i < 4; ++i) {
      const int row = m0 + wm + m * 16 + lg * 4 + i;
      if (MODE == 1) {
        const int bb = row / L_SZ;
        int l2 = row - bb * L_SZ - SHIFT;
        if (l2 < 0) l2 += L_SZ;
        const size_t orow = (size_t)bb * L_SZ + l2;
#pragma unroll
        for (int n = 0; n < 4; ++n) {
          const int col = n0 + wn + n * 16 + lr;
          ((u16*)Cout)[orow * N + col] =
              f2bf(resx[orow * N + col] + acc[m][n][i] + bv4[n]);
        }
      } else if (MODE == 2) {
#pragma unroll
        for (int n = 0; n < 4; ++n) {
          const int col = n0 + wn + n * 16 + lr;
          float v = acc[m][n][i] + bv4[n];
          v = 0.5f * v * (1.0f + erff(v * 0.70710678f));
          ((u16*)Cout)[(size_t)row * N + col] = f2bf(v);
        }
      } else if (MODE == 3) {
#pragma unroll
        for (int n = 0; n < 4; ++n) {
          const int col = n0 + wn + n * 16 + lr;
          ((float*)Cout)[(size_t)row * N + col] =
              acc[m][n][i] + bv4[n] + bf2f(resb2[(size_t)row * N + col]);
        }
      } else {  // MODE 0: plain bf16 store
#pragma unroll
        for (int n = 0; n < 4; ++n) {
          const int col = n0 + wn + n * 16 + lr;
          ((u16*)Cout)[(size_t)row * N + col] = f2bf(acc[m][n][i] + bv4[n]);
        }
      }
    }
  }
}

// ---------------- windowed attention: 2 blocks / window, wave = 1 head -------
// qkv = [row][768] (q|k|v). V staged to LDS via global_load_lds (linear dest,
// chunk-XOR (kk^(kk>>2))&3 folded into SOURCE addr; same XOR on read side).
// V-stage issued BEFORE QK^T so HBM latency hides under compute.
__global__ __launch_bounds__(256) void attn_kernel(const u16* __restrict__ qkv,
                                                   const float* __restrict__ bm,
                                                   u16* __restrict__ out) {
  __shared__ u16 Pls[4][64 * 72];  // per-wave P tile, stride 72 (144B = 9x16B)
  __shared__ u16 Vls[4][64 * 32];  // per-wave V tile [kk][d], chunk-XOR'd
  const int widx = blockIdx.x >> 1;
  const int half = blockIdx.x & 1;
  const int w = widx & (NWIN - 1);
  const int wv = threadIdx.x >> 6;
  const int lane = threadIdx.x & 63;
  const int lr = lane & 15;
  const int lg = lane >> 4;
  const size_t base = (size_t)widx * NW;
  u16* P = Pls[wv];
  u16* Vl = Vls[wv];
  const f32x4 fzero = {0.f, 0.f, 0.f, 0.f};
  const int h = half * 4 + wv;

  // ---- issue V staging first (4 x 16 rows); rows>48 clamp (P==0 there) ----
#pragma unroll
  for (int g = 0; g < 4; ++g) {
    int row = g * 16 + (lane >> 2);
    if (row > NW - 1) row = NW - 1;
    const int sc = (lane & 3) ^ ((row ^ (row >> 2)) & 3);   // pre-swizzled chunk
    gload_lds16(qkv + (base + row) * 768 + 512 + h * 32 + sc * 8, Vl + g * 512);
  }

  bfrag qf[4], kf[4];
#pragma unroll
  for (int m = 0; m < 4; ++m) {
    int r = m * 16 + lr; if (r > NW - 1) r = NW - 1;  // clamp pad rows
    qf[m] = *(const bfrag*)(qkv + (base + r) * 768 + h * 32 + lg * 8);
    kf[m] = *(const bfrag*)(qkv + (base + r) * 768 + 256 + h * 32 + lg * 8);
  }
  f32x4 s[4][4];
#pragma unroll
  for (int m = 0; m < 4; ++m)
#pragma unroll
    for (int n = 0; n < 4; ++n)
      s[m][n] = __builtin_amdgcn_mfma_f32_16x16x32_bf16(qf[m], kf[n], fzero, 0, 0, 0);

  const float* bh = bm + (size_t)(w * NHEADS + h) * (NW * NW);
#pragma unroll
  for (int m = 0; m < 4; ++m) {
#pragma unroll
    for (int i = 0; i < 4; ++i) {
      const int row = m * 16 + lg * 4 + i;
      const int brow = row > NW - 1 ? NW - 1 : row;
      float vals[4];
#pragma unroll
      for (int n = 0; n < 4; ++n) {
        const int c = n * 16 + lr;
        vals[n] = (c < NW) ? (s[m][n][i] * SCALEF + bh[brow * NW + c]) : -1e30f;
      }
      float mx = fmaxf(fmaxf(vals[0], vals[1]), fmaxf(vals[2], vals[3]));
#pragma unroll
      for (int d = 1; d < 16; d <<= 1) mx = fmaxf(mx, __shfl_xor(mx, d));
      float sum = 0.f;
#pragma unroll
      for (int n = 0; n < 4; ++n) { vals[n] = __expf(vals[n] - mx); sum += vals[n]; }
#pragma unroll
      for (int d = 1; d < 16; d <<= 1) sum += __shfl_xor(sum, d);
      const float inv = 1.0f / sum;
#pragma unroll
      for (int n = 0; n < 4; ++n)
        P[row * 72 + n * 16 + lr] = f2bf(vals[n] * inv);
    }
  }
  // ---- wait for V staging (wave-private; no barrier needed) ----
  asm volatile("s_waitcnt vmcnt(0)" ::: "memory");
  // PV: vf gathered from LDS (swizzled chunks)
  f32x4 o[4][2];
#pragma unroll
  for (int m = 0; m < 4; ++m) { o[m][0] = fzero; o[m][1] = fzero; }
#pragma unroll
  for (int s2 = 0; s2 < 2; ++s2) {
    bfrag pf[4], vf[2];
#pragma unroll
    for (int m = 0; m < 4; ++m)
      pf[m] = *(const bfrag*)(P + (m * 16 + lr) * 72 + s2 * 32 + lg * 8);
#pragma unroll
    for (int n = 0; n < 2; ++n) {
      const int d = n * 16 + lr;
      const int cd = d >> 3;                 // global d-chunk
#pragma unroll
      for (int i = 0; i < 8; ++i) {
        const int kk = s2 * 32 + lg * 8 + i;
        const int slot = cd ^ ((kk ^ (kk >> 2)) & 3);
        vf[n][i] = *(const short*)(Vl + kk * 32 + slot * 8 + (d & 7));
      }
    }
#pragma unroll
    for (int m = 0; m < 4; ++m)
#pragma unroll
      for (int n = 0; n < 2; ++n)
        o[m][n] = __builtin_amdgcn_mfma_f32_16x16x32_bf16(pf[m], vf[n],
                                                          o[m][n], 0, 0, 0);
  }
#pragma unroll
  for (int m = 0; m < 4; ++m)
#pragma unroll
    for (int i = 0; i < 4; ++i) {
      const int row = m * 16 + lg * 4 + i;
      if (row < NW) {
#pragma unroll
        for (int n = 0; n < 2; ++n)
          out[(base + row) * C_SZ + h * 32 + n * 16 + lr] = f2bf(o[m][n][i]);
      }
    }
}

// -----------------------------------------------------------------------------
extern "C" void kernel_launch(void* const* d_in, const int* in_sizes, int n_in,
                              void* d_out, int out_size, void* d_ws, size_t ws_size,
                              hipStream_t stream) {
  (void)in_sizes; (void)n_in; (void)out_size;
  const float* x     = (const float*)d_in[0];
  const float* qkvw  = (const float*)d_in[1];
  const float* qkvb  = (const float*)d_in[2];
  const float* projw = (const float*)d_in[3];
  const float* projb = (const float*)d_in[4];
  const float* btab  = (const float*)d_in[5];
  const float* n1w   = (const float*)d_in[6];
  const float* n1b   = (const float*)d_in[7];
  const float* n2w   = (const float*)d_in[8];
  const float* n2b   = (const float*)d_in[9];
  const float* fc1w  = (const float*)d_in[10];
  const float* fc1b  = (const float*)d_in[11];
  const float* fc2w  = (const float*)d_in[12];
  const float* fc2b  = (const float*)d_in[13];
  const int* rel     = (const int*)d_in[14];

  // ---- workspace: head ~110 MB + tail = union{qkv buf 154 MB, scratch 205 MB}
  char* ws = (char*)d_ws;
  size_t off = 0;
  auto alloc = [&](size_t bytes) -> char* {
    char* p = ws + off; off += (bytes + 255) & ~(size_t)255; return p;
  };
  u16* qkvwT   = (u16*)alloc((size_t)768 * 256 * 2);
  u16* projwT  = (u16*)alloc((size_t)256 * 256 * 2);
  u16* fc1wT   = (u16*)alloc((size_t)1024 * 256 * 2);
  u16* fc2wT   = (u16*)alloc((size_t)256 * 1024 * 2);
  float* biasm = (float*)alloc((size_t)NWIN * NHEADS * NW * NW * 4);
  u16* bufh    = (u16*)alloc((size_t)M_SZ * C_SZ * 2);   // h / attn-out / h2
  u16* x2b     = (u16*)alloc((size_t)M_SZ * C_SZ * 2);   // bf16 residual x2

  char* tail = ws + off;
  u16* qkvbuf   = (u16*)tail;                            // 154.1 MB
  u16* scratch2 = (u16*)tail;                            // 205.5 MB (overlays)
  const size_t full_scr = (size_t)M_SZ * HID_SZ * 2;
  const int nch = (ws_size >= off + full_scr) ? 1 : 4;   // mlp chunking
  const int mch = M_SZ / nch;

  transpose_kernel<<<(256 * 768 + 255) / 256, 256, 0, stream>>>(qkvw, qkvwT, 256, 768);
  transpose_kernel<<<(256 * 256 + 255) / 256, 256, 0, stream>>>(projw, projwT, 256, 256);
  transpose_kernel<<<(256 * 1024 + 255) / 256, 256, 0, stream>>>(fc1w, fc1wT, 256, 1024);
  transpose_kernel<<<(1024 * 256 + 255) / 256, 256, 0, stream>>>(fc2w, fc2wT, 1024, 256);
  bias_kernel<<<(NWIN * NHEADS * NW * NW + 255) / 256, 256, 0, stream>>>(btab, rel, biasm);

  // LN1 + roll -> bufh (rolled window space)
  ln1_kernel<<<M_SZ / 16, 256, 0, stream>>>(x, n1w, n1b, bufh);

  // qkv projection -> qkvbuf [row][768], fully coalesced
  gemm_kernel<0><<<(768 / BN) * (M_SZ / BM), 256, 0, stream>>>(
      bufh, qkvwT, qkvb, 768, 256, qkvbuf, nullptr, nullptr);

  // windowed attention -> bufh (2 blocks per window, wave = 1 head)
  attn_kernel<<<B_SZ * NWIN * 2, 256, 0, stream>>>(qkvbuf, biasm, bufh);

  // proj + un-roll + x residual -> bf16 x2
  gemm_kernel<1><<<(256 / BN) * (M_SZ / BM), 256, 0, stream>>>(
      bufh, projwT, projb, 256, 256, x2b, x, nullptr);

  // MLP per chunk: ln2 -> bufh; fc1+GELU -> scratch2; fc2 + residual -> d_out
  for (int q = 0; q < nch; ++q) {
    const size_t roff = (size_t)q * mch;
    ln2_kernel<<<mch / 16, 256, 0, stream>>>(x2b + roff * C_SZ, n2w, n2b,
                                             bufh + roff * C_SZ);
    gemm_kernel<2><<<(HID_SZ / BN) * (mch / BM), 256, 0, stream>>>(
        bufh + roff * C_SZ, fc1wT, fc1b, 1024, 256, scratch2, nullptr, nullptr);
    gemm_kernel<3><<<(256 / BN) * (mch / BM), 256, 0, stream>>>(
        scratch2, fc2wT, fc2b, 256, 1024, (float*)d_out + roff * C_SZ,
        nullptr, x2b + roff * C_SZ);
  }
}